// Round 3
// baseline (357.639 us; speedup 1.0000x reference)
//
#include <hip/hip_runtime.h>
#include <hip/hip_bf16.h>

// Problem: B=2, T=2048, C=1024, H=16, D=64 causal self-attention fwd.
// All inputs fp32; output fp32. Compute in bf16 MFMA (threshold = 2% of max|ref|).

namespace {

constexpr int TT = 2048;
constexpr int CC = 1024;
constexpr int HH = 16;
constexpr int DD = 64;

using bf16x8 = __attribute__((ext_vector_type(8))) __bf16;
using f32x4  = __attribute__((ext_vector_type(4))) float;
using us8    = __attribute__((ext_vector_type(8))) unsigned short;

__device__ __forceinline__ unsigned short f2b(float f) {
  unsigned u = __float_as_uint(f);
  u += 0x7fffu + ((u >> 16) & 1u);   // RNE
  return (unsigned short)(u >> 16);
}

} // namespace

// ---------------- fp32 -> bf16 conversion (vectorized) ----------------
__global__ void k_cvt(const float* __restrict__ in, unsigned short* __restrict__ out, int n4) {
  int i = blockIdx.x * 256 + threadIdx.x;
  if (i >= n4) return;
  float4 v = reinterpret_cast<const float4*>(in)[i];
  ushort4 o;
  o.x = f2b(v.x); o.y = f2b(v.y); o.z = f2b(v.z); o.w = f2b(v.w);
  reinterpret_cast<ushort4*>(out)[i] = o;
}

// ---------------- GEMM: out[m,n] = sum_k A[m,k]*W[n,k] + bias[n] ----------------
// A: [4096][1024] bf16, W: [1024][1024] bf16 (row = out channel), 128x128 tile, BK=32.
// mode 0: dst bf16 [B,H,T,D]   (Q, K)
// mode 1: dst bf16 [B,H,D,T]   (V transposed)
// mode 2: dst f32  [4096][1024] (final projection)
__global__ __launch_bounds__(256) void k_gemm_bt(
    const unsigned short* __restrict__ A,
    const unsigned short* __restrict__ W,
    const float* __restrict__ bias,
    void* __restrict__ dst, const int mode)
{
  __shared__ unsigned short la[128 * 40];  // +8 pad kills bank conflicts
  __shared__ unsigned short lb[128 * 40];
  const int tid = threadIdx.x;
  const int lane = tid & 63;
  const int wid = tid >> 6;
  const int l15 = lane & 15, lg = lane >> 4;
  const int wm = (wid & 1) * 64, wn = (wid >> 1) * 64;
  const int bm = blockIdx.x, bn = blockIdx.y;

  f32x4 acc[4][4];
#pragma unroll
  for (int i = 0; i < 4; ++i)
#pragma unroll
    for (int j = 0; j < 4; ++j) acc[i][j] = f32x4{0.f, 0.f, 0.f, 0.f};

  for (int kt = 0; kt < CC / 32; ++kt) {
    __syncthreads();
#pragma unroll
    for (int s = 0; s < 2; ++s) {
      const int c = tid + s * 256;           // 512 16B chunks per tile
      const int row = c >> 2, ko = (c & 3) * 8;
      us8 av = *reinterpret_cast<const us8*>(&A[(bm * 128 + row) * CC + kt * 32 + ko]);
      us8 bv = *reinterpret_cast<const us8*>(&W[(bn * 128 + row) * CC + kt * 32 + ko]);
      *reinterpret_cast<us8*>(&la[row * 40 + ko]) = av;
      *reinterpret_cast<us8*>(&lb[row * 40 + ko]) = bv;
    }
    __syncthreads();
    bf16x8 af[4], bf[4];
#pragma unroll
    for (int mi = 0; mi < 4; ++mi)
      af[mi] = __builtin_bit_cast(bf16x8,
        *reinterpret_cast<const us8*>(&la[(wm + mi * 16 + l15) * 40 + lg * 8]));
#pragma unroll
    for (int ni = 0; ni < 4; ++ni)
      bf[ni] = __builtin_bit_cast(bf16x8,
        *reinterpret_cast<const us8*>(&lb[(wn + ni * 16 + l15) * 40 + lg * 8]));
#pragma unroll
    for (int mi = 0; mi < 4; ++mi)
#pragma unroll
      for (int ni = 0; ni < 4; ++ni)
        acc[mi][ni] = __builtin_amdgcn_mfma_f32_16x16x32_bf16(af[mi], bf[ni], acc[mi][ni], 0, 0, 0);
  }

  // epilogue: C/D layout col = lane&15, row = (lane>>4)*4 + r (m89-verified)
#pragma unroll
  for (int ni = 0; ni < 4; ++ni) {
    const int n = bn * 128 + wn + ni * 16 + l15;
    const float bv = bias[n];
#pragma unroll
    for (int mi = 0; mi < 4; ++mi) {
#pragma unroll
      for (int r = 0; r < 4; ++r) {
        const int m = bm * 128 + wm + mi * 16 + lg * 4 + r;
        const float val = acc[mi][ni][r] + bv;
        if (mode == 2) {
          reinterpret_cast<float*>(dst)[m * CC + n] = val;
        } else {
          const unsigned short bb = f2b(val);
          const int b = m >> 11, t = m & (TT - 1);
          const int h = n >> 6, d = n & (DD - 1);
          if (mode == 0)
            reinterpret_cast<unsigned short*>(dst)[((b * HH + h) * TT + t) * DD + d] = bb;
          else
            reinterpret_cast<unsigned short*>(dst)[((b * HH + h) * DD + d) * TT + t] = bb;
        }
      }
    }
  }
}

// ---------------- flash attention: 1 wave/block, 32 q-rows, KBLK=64 ----------------
__global__ __launch_bounds__(64) void k_attn(
    const unsigned short* __restrict__ Q,   // [BH][T][D] bf16
    const unsigned short* __restrict__ K,   // [BH][T][D] bf16
    const unsigned short* __restrict__ VT,  // [BH][D][T] bf16
    unsigned short* __restrict__ Y)         // [B][T][C] bf16
{
  __shared__ unsigned short pl[2][16][80];  // P tile, padded rows (160B, 16B-aligned)
  const int lane = threadIdx.x;
  const int l15 = lane & 15, lg = lane >> 4;
  const int bh = blockIdx.y;
  const int qb0 = blockIdx.x * 32;
  const int b = bh >> 4, h = bh & 15;

  const unsigned short* Qh = Q + bh * TT * DD;
  const unsigned short* Kh = K + bh * TT * DD;
  const unsigned short* Vh = VT + bh * DD * TT;

  // Q fragments: A[row=l&15][k=(l>>4)*8+j], two K-chunks of 32 over D=64
  bf16x8 qf[2][2];
#pragma unroll
  for (int qi = 0; qi < 2; ++qi)
#pragma unroll
    for (int kk = 0; kk < 2; ++kk)
      qf[qi][kk] = __builtin_bit_cast(bf16x8,
        *reinterpret_cast<const us8*>(&Qh[(qb0 + qi * 16 + l15) * DD + kk * 32 + lg * 8]));

  f32x4 o[2][4];
  float mr[2][4], lr[2][4];
#pragma unroll
  for (int qi = 0; qi < 2; ++qi) {
#pragma unroll
    for (int r = 0; r < 4; ++r) { mr[qi][r] = -INFINITY; lr[qi][r] = 0.f; }
#pragma unroll
    for (int dc = 0; dc < 4; ++dc) o[qi][dc] = f32x4{0.f, 0.f, 0.f, 0.f};
  }

  const int nkt = (qb0 + 95) >> 6;  // key tiles covering 0..qb0+31
  for (int kt = 0; kt < nkt; ++kt) {
    const int kbase = kt * 64;
    bf16x8 kf[4][2];
#pragma unroll
    for (int f = 0; f < 4; ++f)
#pragma unroll
      for (int kk = 0; kk < 2; ++kk)
        kf[f][kk] = __builtin_bit_cast(bf16x8,
          *reinterpret_cast<const us8*>(&Kh[(kbase + f * 16 + l15) * DD + kk * 32 + lg * 8]));

    // S = Q K^T : C col = key (l&15), rows = queries (lg*4+r)
    f32x4 s[2][4];
#pragma unroll
    for (int qi = 0; qi < 2; ++qi)
#pragma unroll
      for (int f = 0; f < 4; ++f) {
        f32x4 t0 = __builtin_amdgcn_mfma_f32_16x16x32_bf16(qf[qi][0], kf[f][0], f32x4{0.f,0.f,0.f,0.f}, 0, 0, 0);
        s[qi][f] = __builtin_amdgcn_mfma_f32_16x16x32_bf16(qf[qi][1], kf[f][1], t0, 0, 0, 0);
      }

#pragma unroll
    for (int qi = 0; qi < 2; ++qi) {
      float cm[4] = {-INFINITY, -INFINITY, -INFINITY, -INFINITY};
#pragma unroll
      for (int f = 0; f < 4; ++f) {
        const int key = kbase + f * 16 + l15;
#pragma unroll
        for (int r = 0; r < 4; ++r) {
          const int qr = qb0 + qi * 16 + lg * 4 + r;
          float sv = s[qi][f][r] * 0.125f;           // 1/sqrt(64)
          sv = (key <= qr) ? sv : -INFINITY;
          s[qi][f][r] = sv;
          cm[r] = fmaxf(cm[r], sv);
        }
      }
#pragma unroll
      for (int r = 0; r < 4; ++r) {
        cm[r] = fmaxf(cm[r], __shfl_xor(cm[r], 1));
        cm[r] = fmaxf(cm[r], __shfl_xor(cm[r], 2));
        cm[r] = fmaxf(cm[r], __shfl_xor(cm[r], 4));
        cm[r] = fmaxf(cm[r], __shfl_xor(cm[r], 8));
        const float mn = fmaxf(mr[qi][r], cm[r]);
        const float alpha = __expf(mr[qi][r] - mn);  // first iter: exp(-inf)=0
        mr[qi][r] = mn;
        float rs = 0.f;
#pragma unroll
        for (int f = 0; f < 4; ++f) {
          const float p = __expf(s[qi][f][r] - mn);  // masked -> 0
          rs += p;
          pl[qi][lg * 4 + r][f * 16 + l15] = f2b(p);
        }
        rs += __shfl_xor(rs, 1);
        rs += __shfl_xor(rs, 2);
        rs += __shfl_xor(rs, 4);
        rs += __shfl_xor(rs, 8);
        lr[qi][r] = lr[qi][r] * alpha + rs;
#pragma unroll
        for (int dc = 0; dc < 4; ++dc) o[qi][dc][r] *= alpha;
      }
    }
    asm volatile("s_waitcnt lgkmcnt(0)" ::: "memory");  // P writes visible wave-wide

    // PV: A = P (rows=queries, k=keys), B = V^T read (col=d, k=keys)
    bf16x8 vf[2][4];
#pragma unroll
    for (int kk = 0; kk < 2; ++kk)
#pragma unroll
      for (int dc = 0; dc < 4; ++dc)
        vf[kk][dc] = __builtin_bit_cast(bf16x8,
          *reinterpret_cast<const us8*>(&Vh[(dc * 16 + l15) * TT + kbase + kk * 32 + lg * 8]));
#pragma unroll
    for (int qi = 0; qi < 2; ++qi) {
      bf16x8 pa[2];
#pragma unroll
      for (int kk = 0; kk < 2; ++kk)
        pa[kk] = __builtin_bit_cast(bf16x8,
          *reinterpret_cast<const us8*>(&pl[qi][l15][kk * 32 + lg * 8]));
#pragma unroll
      for (int dc = 0; dc < 4; ++dc) {
        o[qi][dc] = __builtin_amdgcn_mfma_f32_16x16x32_bf16(pa[0], vf[0][dc], o[qi][dc], 0, 0, 0);
        o[qi][dc] = __builtin_amdgcn_mfma_f32_16x16x32_bf16(pa[1], vf[1][dc], o[qi][dc], 0, 0, 0);
      }
    }
  }

  // epilogue: normalize and write y[b][t][h*64+d] bf16
#pragma unroll
  for (int qi = 0; qi < 2; ++qi)
#pragma unroll
    for (int r = 0; r < 4; ++r) {
      const float inv = 1.f / lr[qi][r];
      const int t = qb0 + qi * 16 + lg * 4 + r;
#pragma unroll
      for (int dc = 0; dc < 4; ++dc)
        Y[(b * TT + t) * CC + h * DD + dc * 16 + l15] = f2b(o[qi][dc][r] * inv);
    }
}

extern "C" void kernel_launch(void* const* d_in, const int* in_sizes, int n_in,
                              void* d_out, int out_size, void* d_ws, size_t ws_size,
                              hipStream_t stream) {
  const float* x  = (const float*)d_in[0];
  const float* Wq = (const float*)d_in[1];
  const float* bq = (const float*)d_in[2];
  const float* Wk = (const float*)d_in[3];
  const float* bk = (const float*)d_in[4];
  const float* Wv = (const float*)d_in[5];
  const float* bv = (const float*)d_in[6];
  const float* Wo = (const float*)d_in[7];
  const float* bo = (const float*)d_in[8];
  float* out = (float*)d_out;

  unsigned short* ws  = (unsigned short*)d_ws;
  unsigned short* xb  = ws;               // x bf16       [4096][1024]
  unsigned short* wqb = xb  + 4194304;    // Wq bf16
  unsigned short* wkb = wqb + 1048576;
  unsigned short* wvb = wkb + 1048576;
  unsigned short* wob = wvb + 1048576;
  unsigned short* qb  = wob + 1048576;    // Q  [BH][T][D]
  unsigned short* kb  = qb  + 4194304;    // K  [BH][T][D]
  unsigned short* vt  = kb  + 4194304;    // V^T [BH][D][T]
  unsigned short* yb  = xb;               // attn out [B][T][C] — aliases xb (dead after V GEMM)

  k_cvt<<<4096, 256, 0, stream>>>(x,  xb,  1048576);
  k_cvt<<<1024, 256, 0, stream>>>(Wq, wqb, 262144);
  k_cvt<<<1024, 256, 0, stream>>>(Wk, wkb, 262144);
  k_cvt<<<1024, 256, 0, stream>>>(Wv, wvb, 262144);
  k_cvt<<<1024, 256, 0, stream>>>(Wo, wob, 262144);

  dim3 gg(32, 8);
  k_gemm_bt<<<gg, 256, 0, stream>>>(xb, wqb, bq, qb, 0);
  k_gemm_bt<<<gg, 256, 0, stream>>>(xb, wkb, bk, kb, 0);
  k_gemm_bt<<<gg, 256, 0, stream>>>(xb, wvb, bv, vt, 1);

  k_attn<<<dim3(TT / 32, 32), 64, 0, stream>>>(qb, kb, vt, yb);

  k_gemm_bt<<<gg, 256, 0, stream>>>(yb, wob, bo, out, 2);
}

// Round 6
// 272.532 us; speedup vs baseline: 1.3123x; 1.3123x over previous
//
#include <hip/hip_runtime.h>
#include <hip/hip_bf16.h>

// Problem: B=2, T=2048, C=1024, H=16, D=64 causal self-attention fwd.
// All inputs fp32; output fp32. Compute in bf16 MFMA (threshold = 2% of max|ref|).

namespace {

constexpr int TT = 2048;
constexpr int CC = 1024;
constexpr int HH = 16;
constexpr int DD = 64;

using bf16x8 = __attribute__((ext_vector_type(8))) __bf16;
using bf16x4 = __attribute__((ext_vector_type(4))) __bf16;
using f32x4  = __attribute__((ext_vector_type(4))) float;
using us8    = __attribute__((ext_vector_type(8))) unsigned short;

__device__ __forceinline__ unsigned short f2b(float f) {
  unsigned u = __float_as_uint(f);
  u += 0x7fffu + ((u >> 16) & 1u);   // RNE
  return (unsigned short)(u >> 16);
}

#if __has_builtin(__builtin_amdgcn_exp2f)
#define FEXP2 __builtin_amdgcn_exp2f
#else
#define FEXP2 exp2f
#endif

// 1/sqrt(64) * log2(e): softmax computed in exp2 domain
#define SCALE2 0.18033688011112042f

} // namespace

// ---------------- fp32 -> bf16 conversion (vectorized) ----------------
__global__ void k_cvt(const float* __restrict__ in, unsigned short* __restrict__ out, int n4) {
  int i = blockIdx.x * 256 + threadIdx.x;
  if (i >= n4) return;
  float4 v = reinterpret_cast<const float4*>(in)[i];
  ushort4 o;
  o.x = f2b(v.x); o.y = f2b(v.y); o.z = f2b(v.z); o.w = f2b(v.w);
  reinterpret_cast<ushort4*>(out)[i] = o;
}

// ---------------- GEMM: out[m,n] = sum_k A[m,k]*W[n,k] + bias[n] ----------------
// (unchanged from the passing round-3 kernel)
__global__ __launch_bounds__(256) void k_gemm_bt(
    const unsigned short* __restrict__ A,
    const unsigned short* __restrict__ W,
    const float* __restrict__ bias,
    void* __restrict__ dst, const int mode)
{
  __shared__ unsigned short la[128 * 40];
  __shared__ unsigned short lb[128 * 40];
  const int tid = threadIdx.x;
  const int lane = tid & 63;
  const int wid = tid >> 6;
  const int l15 = lane & 15, lg = lane >> 4;
  const int wm = (wid & 1) * 64, wn = (wid >> 1) * 64;
  const int bm = blockIdx.x, bn = blockIdx.y;

  f32x4 acc[4][4];
#pragma unroll
  for (int i = 0; i < 4; ++i)
#pragma unroll
    for (int j = 0; j < 4; ++j) acc[i][j] = f32x4{0.f, 0.f, 0.f, 0.f};

  for (int kt = 0; kt < CC / 32; ++kt) {
    __syncthreads();
#pragma unroll
    for (int s = 0; s < 2; ++s) {
      const int c = tid + s * 256;
      const int row = c >> 2, ko = (c & 3) * 8;
      us8 av = *reinterpret_cast<const us8*>(&A[(bm * 128 + row) * CC + kt * 32 + ko]);
      us8 bv = *reinterpret_cast<const us8*>(&W[(bn * 128 + row) * CC + kt * 32 + ko]);
      *reinterpret_cast<us8*>(&la[row * 40 + ko]) = av;
      *reinterpret_cast<us8*>(&lb[row * 40 + ko]) = bv;
    }
    __syncthreads();
    bf16x8 af[4], bf[4];
#pragma unroll
    for (int mi = 0; mi < 4; ++mi)
      af[mi] = __builtin_bit_cast(bf16x8,
        *reinterpret_cast<const us8*>(&la[(wm + mi * 16 + l15) * 40 + lg * 8]));
#pragma unroll
    for (int ni = 0; ni < 4; ++ni)
      bf[ni] = __builtin_bit_cast(bf16x8,
        *reinterpret_cast<const us8*>(&lb[(wn + ni * 16 + l15) * 40 + lg * 8]));
#pragma unroll
    for (int mi = 0; mi < 4; ++mi)
#pragma unroll
      for (int ni = 0; ni < 4; ++ni)
        acc[mi][ni] = __builtin_amdgcn_mfma_f32_16x16x32_bf16(af[mi], bf[ni], acc[mi][ni], 0, 0, 0);
  }

#pragma unroll
  for (int ni = 0; ni < 4; ++ni) {
    const int n = bn * 128 + wn + ni * 16 + l15;
    const float bv = bias[n];
#pragma unroll
    for (int mi = 0; mi < 4; ++mi) {
#pragma unroll
      for (int r = 0; r < 4; ++r) {
        const int m = bm * 128 + wm + mi * 16 + lg * 4 + r;
        const float val = acc[mi][ni][r] + bv;
        if (mode == 2) {
          reinterpret_cast<float*>(dst)[m * CC + n] = val;
        } else {
          const unsigned short bb = f2b(val);
          const int b = m >> 11, t = m & (TT - 1);
          const int h = n >> 6, d = n & (DD - 1);
          if (mode == 0)
            reinterpret_cast<unsigned short*>(dst)[((b * HH + h) * TT + t) * DD + d] = bb;
          else
            reinterpret_cast<unsigned short*>(dst)[((b * HH + h) * DD + d) * TT + t] = bb;
        }
      }
    }
  }
}

// ---------------- flash attention v2 ----------------
// 1 wave/block; each wave owns the q-block PAIR (p, 63-p) -> uniform 33 k-tiles/wave.
// Swapped QK^T (mfma(K,Q)): lane holds 16 key-scores of ONE query column ->
// softmax reduce = in-lane chain + 2 shfl; K/V fragment loads shared by both sets.
__global__ __launch_bounds__(64) void k_attn(
    const unsigned short* __restrict__ Q,   // [BH][T][D] bf16
    const unsigned short* __restrict__ K,   // [BH][T][D] bf16
    const unsigned short* __restrict__ VT,  // [BH][D][T] bf16
    unsigned short* __restrict__ Y)         // [B][T][C] bf16
{
  __shared__ unsigned short pl[2][2][16][80];  // [set][qi][q-row][key], padded rows
  const int lane = threadIdx.x;
  const int l15 = lane & 15, lg = lane >> 4;
  const int bh = blockIdx.y;
  const int b = bh >> 4, h = bh & 15;
  const int p = blockIdx.x;                // 0..31
  const int qb0A = p * 32;                 // low q-block
  const int qb0B = (63 - p) * 32;          // high q-block
  const int nktA = (qb0A + 95) >> 6;
  const int nktB = (qb0B + 95) >> 6;       // nktA + nktB == 33 for all p

  const unsigned short* Qh = Q + bh * TT * DD;
  const unsigned short* Kh = K + bh * TT * DD;
  const unsigned short* Vh = VT + bh * DD * TT;

  auto ldq = [&](bf16x8 (&qf)[2][2], int qb0) {
#pragma unroll
    for (int qi = 0; qi < 2; ++qi)
#pragma unroll
      for (int kk = 0; kk < 2; ++kk)
        qf[qi][kk] = __builtin_bit_cast(bf16x8,
          *reinterpret_cast<const us8*>(&Qh[(qb0 + qi * 16 + l15) * DD + kk * 32 + lg * 8]));
  };
  auto ldk = [&](bf16x8 (&kf)[4][2], int kb) {
#pragma unroll
    for (int f = 0; f < 4; ++f)
#pragma unroll
      for (int kk = 0; kk < 2; ++kk)
        kf[f][kk] = __builtin_bit_cast(bf16x8,
          *reinterpret_cast<const us8*>(&Kh[(kb + f * 16 + l15) * DD + kk * 32 + lg * 8]));
  };
  auto ldv = [&](bf16x8 (&vf)[2][4], int kb) {
#pragma unroll
    for (int kk = 0; kk < 2; ++kk)
#pragma unroll
      for (int dc = 0; dc < 4; ++dc)
        vf[kk][dc] = __builtin_bit_cast(bf16x8,
          *reinterpret_cast<const us8*>(&Vh[(dc * 16 + l15) * TT + kb + kk * 32 + lg * 8]));
  };

  bf16x8 qfA[2][2], qfB[2][2];
  ldq(qfA, qb0A); ldq(qfB, qb0B);

  f32x4 oA[2][4], oB[2][4];
  float mrA[2], lrA[2], mrB[2], lrB[2];
#pragma unroll
  for (int qi = 0; qi < 2; ++qi) {
    mrA[qi] = -INFINITY; lrA[qi] = 0.f;
    mrB[qi] = -INFINITY; lrB[qi] = 0.f;
#pragma unroll
    for (int dc = 0; dc < 4; ++dc) {
      oA[qi][dc] = f32x4{0.f, 0.f, 0.f, 0.f};
      oB[qi][dc] = f32x4{0.f, 0.f, 0.f, 0.f};
    }
  }

  auto processSet = [&](const int qb0, const bf16x8 (&qf)[2][2], f32x4 (&o)[2][4],
                        float (&mr)[2], float (&lr)[2],
                        unsigned short (&plS)[2][16][80],
                        const bf16x8 (&kf)[4][2], const bf16x8 (&vf)[2][4],
                        const int kbase) {
    // S^T = K Q^T : C[row=key=lg*4+r][col=q=l15]
    f32x4 s[2][4];
#pragma unroll
    for (int qi = 0; qi < 2; ++qi)
#pragma unroll
      for (int f = 0; f < 4; ++f) {
        f32x4 t0 = __builtin_amdgcn_mfma_f32_16x16x32_bf16(kf[f][0], qf[qi][0],
                                                           f32x4{0.f,0.f,0.f,0.f}, 0, 0, 0);
        s[qi][f] = __builtin_amdgcn_mfma_f32_16x16x32_bf16(kf[f][1], qf[qi][1], t0, 0, 0, 0);
      }
    const bool needMask = (kbase + 63 > qb0);  // wave-uniform
#pragma unroll
    for (int qi = 0; qi < 2; ++qi) {
      const int qg = qb0 + qi * 16 + l15;
      float sv[4][4];
      float mt = -INFINITY;
#pragma unroll
      for (int f = 0; f < 4; ++f)
#pragma unroll
        for (int r = 0; r < 4; ++r) {
          float v = s[qi][f][r] * SCALE2;
          if (needMask) v = (kbase + f * 16 + lg * 4 + r <= qg) ? v : -INFINITY;
          sv[f][r] = v;
          mt = fmaxf(mt, v);
        }
      mt = fmaxf(mt, __shfl_xor(mt, 16));
      mt = fmaxf(mt, __shfl_xor(mt, 32));
      const float mn = fmaxf(mr[qi], mt);
      const float al = FEXP2(mr[qi] - mn);   // first tile: exp2(-inf)=0
      mr[qi] = mn;
      float rs = 0.f;
#pragma unroll
      for (int f = 0; f < 4; ++f) {
        const float p0 = FEXP2(sv[f][0] - mn), p1 = FEXP2(sv[f][1] - mn);
        const float p2 = FEXP2(sv[f][2] - mn), p3 = FEXP2(sv[f][3] - mn);
        rs += (p0 + p1) + (p2 + p3);
        bf16x4 pk;
        pk[0] = (__bf16)p0; pk[1] = (__bf16)p1; pk[2] = (__bf16)p2; pk[3] = (__bf16)p3;
        *reinterpret_cast<bf16x4*>(&plS[qi][l15][f * 16 + lg * 4]) = pk;  // keys contiguous
      }
      rs += __shfl_xor(rs, 16);
      rs += __shfl_xor(rs, 32);
      lr[qi] = lr[qi] * al + rs;
      float alr[4];
#pragma unroll
      for (int r = 0; r < 4; ++r) alr[r] = __shfl(al, lg * 4 + r);  // q remap for C-layout
#pragma unroll
      for (int dc = 0; dc < 4; ++dc)
#pragma unroll
        for (int r = 0; r < 4; ++r) o[qi][dc][r] *= alr[r];
    }
    asm volatile("s_waitcnt lgkmcnt(0)" ::: "memory");
    __builtin_amdgcn_sched_barrier(0);
    // PV: A = P[row=q][k=key] from LDS, B = V^T fragments
#pragma unroll
    for (int qi = 0; qi < 2; ++qi) {
      const bf16x8 pa0 = __builtin_bit_cast(bf16x8,
        *reinterpret_cast<const us8*>(&plS[qi][l15][lg * 8]));
      const bf16x8 pa1 = __builtin_bit_cast(bf16x8,
        *reinterpret_cast<const us8*>(&plS[qi][l15][32 + lg * 8]));
#pragma unroll
      for (int dc = 0; dc < 4; ++dc) {
        o[qi][dc] = __builtin_amdgcn_mfma_f32_16x16x32_bf16(pa0, vf[0][dc], o[qi][dc], 0, 0, 0);
        o[qi][dc] = __builtin_amdgcn_mfma_f32_16x16x32_bf16(pa1, vf[1][dc], o[qi][dc], 0, 0, 0);
      }
    }
  };

  // main loop, unrolled by 2 for register double-buffered K fragments
  bf16x8 kf0[4][2], kf1[4][2];
  ldk(kf0, 0);
  for (int kt = 0; kt < nktB; kt += 2) {
    bf16x8 vf0[2][4];
    ldv(vf0, kt * 64);
    const int nx1 = (kt + 1 < nktB) ? kt + 1 : nktB - 1;
    ldk(kf1, nx1 * 64);
    processSet(qb0B, qfB, oB, mrB, lrB, pl[0], kf0, vf0, kt * 64);
    if (kt < nktA)
      processSet(qb0A, qfA, oA, mrA, lrA, pl[1], kf0, vf0, kt * 64);
    if (kt + 1 < nktB) {
      bf16x8 vf1[2][4];
      ldv(vf1, (kt + 1) * 64);
      const int nx2 = (kt + 2 < nktB) ? kt + 2 : nktB - 1;
      ldk(kf0, nx2 * 64);
      processSet(qb0B, qfB, oB, mrB, lrB, pl[0], kf1, vf1, (kt + 1) * 64);
      if (kt + 1 < nktA)
        processSet(qb0A, qfA, oA, mrA, lrA, pl[1], kf1, vf1, (kt + 1) * 64);
    }
  }

  auto epi = [&](int qb0, f32x4 (&o)[2][4], float (&lr)[2]) {
#pragma unroll
    for (int qi = 0; qi < 2; ++qi) {
      float linv[4];
#pragma unroll
      for (int r = 0; r < 4; ++r) linv[r] = 1.f / __shfl(lr[qi], lg * 4 + r);
#pragma unroll
      for (int r = 0; r < 4; ++r) {
        const int t = qb0 + qi * 16 + lg * 4 + r;
#pragma unroll
        for (int dc = 0; dc < 4; ++dc)
          Y[(b * TT + t) * CC + h * DD + dc * 16 + l15] = f2b(o[qi][dc][r] * linv[r]);
      }
    }
  };
  epi(qb0B, oB, lrB);
  epi(qb0A, oA, lrA);
}

extern "C" void kernel_launch(void* const* d_in, const int* in_sizes, int n_in,
                              void* d_out, int out_size, void* d_ws, size_t ws_size,
                              hipStream_t stream) {
  const float* x  = (const float*)d_in[0];
  const float* Wq = (const float*)d_in[1];
  const float* bq = (const float*)d_in[2];
  const float* Wk = (const float*)d_in[3];
  const float* bk = (const float*)d_in[4];
  const float* Wv = (const float*)d_in[5];
  const float* bv = (const float*)d_in[6];
  const float* Wo = (const float*)d_in[7];
  const float* bo = (const float*)d_in[8];
  float* out = (float*)d_out;

  unsigned short* ws  = (unsigned short*)d_ws;
  unsigned short* xb  = ws;               // x bf16       [4096][1024]
  unsigned short* wqb = xb  + 4194304;    // Wq bf16
  unsigned short* wkb = wqb + 1048576;
  unsigned short* wvb = wkb + 1048576;
  unsigned short* wob = wvb + 1048576;
  unsigned short* qb  = wob + 1048576;    // Q  [BH][T][D]
  unsigned short* kb  = qb  + 4194304;    // K  [BH][T][D]
  unsigned short* vt  = kb  + 4194304;    // V^T [BH][D][T]
  unsigned short* yb  = xb;               // attn out [B][T][C] — aliases xb (dead after V GEMM)

  k_cvt<<<4096, 256, 0, stream>>>(x,  xb,  1048576);
  k_cvt<<<1024, 256, 0, stream>>>(Wq, wqb, 262144);
  k_cvt<<<1024, 256, 0, stream>>>(Wk, wkb, 262144);
  k_cvt<<<1024, 256, 0, stream>>>(Wv, wvb, 262144);
  k_cvt<<<1024, 256, 0, stream>>>(Wo, wob, 262144);

  dim3 gg(32, 8);
  k_gemm_bt<<<gg, 256, 0, stream>>>(xb, wqb, bq, qb, 0);
  k_gemm_bt<<<gg, 256, 0, stream>>>(xb, wkb, bk, kb, 0);
  k_gemm_bt<<<gg, 256, 0, stream>>>(xb, wvb, bv, vt, 1);

  k_attn<<<dim3(32, 32), 64, 0, stream>>>(qb, kb, vt, yb);

  k_gemm_bt<<<gg, 256, 0, stream>>>(yb, wob, bo, out, 2);
}

// Round 7
// 219.524 us; speedup vs baseline: 1.6292x; 1.2415x over previous
//
#include <hip/hip_runtime.h>
#include <hip/hip_bf16.h>

// Problem: B=2, T=2048, C=1024, H=16, D=64 causal self-attention fwd.
// All inputs fp32; output fp32. Compute in bf16 MFMA (threshold = 2% of max|ref|).

namespace {

constexpr int TT = 2048;
constexpr int CC = 1024;
constexpr int HH = 16;
constexpr int DD = 64;

using bf16x8 = __attribute__((ext_vector_type(8))) __bf16;
using bf16x4 = __attribute__((ext_vector_type(4))) __bf16;
using f32x4  = __attribute__((ext_vector_type(4))) float;
using us8    = __attribute__((ext_vector_type(8))) unsigned short;

__device__ __forceinline__ unsigned short f2b(float f) {
  unsigned u = __float_as_uint(f);
  u += 0x7fffu + ((u >> 16) & 1u);   // RNE
  return (unsigned short)(u >> 16);
}

// async global->LDS, 16B per lane; LDS dest is wave-uniform base + lane*16
__device__ __forceinline__ void gload16(const void* g, void* l) {
  __builtin_amdgcn_global_load_lds(
      (const __attribute__((address_space(1))) void*)g,
      (__attribute__((address_space(3))) void*)l, 16, 0, 0);
}

#if __has_builtin(__builtin_amdgcn_exp2f)
#define FEXP2 __builtin_amdgcn_exp2f
#else
#define FEXP2 exp2f
#endif

// 1/sqrt(64) * log2(e): softmax computed in exp2 domain
#define SCALE2 0.18033688011112042f

} // namespace

// ---------------- fp32 -> bf16 conversion (vectorized) ----------------
__global__ void k_cvt(const float* __restrict__ in, unsigned short* __restrict__ out, int n4) {
  int i = blockIdx.x * 256 + threadIdx.x;
  if (i >= n4) return;
  float4 v = reinterpret_cast<const float4*>(in)[i];
  ushort4 o;
  o.x = f2b(v.x); o.y = f2b(v.y); o.z = f2b(v.z); o.w = f2b(v.w);
  reinterpret_cast<ushort4*>(out)[i] = o;
}

// ---------------- fused QKV GEMM ----------------
// out[m,n] = sum_k x[m,k]*W[n,k] + bias[n] for W in {Wq,Wk,Wv} selected by blockIdx.y>>3.
// 128x128 tile, BK=32, global_load_lds staging into linear [128][32] LDS (m97 structure).
// grid (32, 24) = 768 blocks -> 3 blocks/CU.
__global__ __launch_bounds__(256, 3) void k_gemm_qkv(
    const unsigned short* __restrict__ A,    // x bf16 [4096][1024]
    const unsigned short* __restrict__ Wq,
    const unsigned short* __restrict__ Wk,
    const unsigned short* __restrict__ Wv,
    const float* __restrict__ bq,
    const float* __restrict__ bk,
    const float* __restrict__ bv,
    unsigned short* __restrict__ qd,         // [BH][T][D]
    unsigned short* __restrict__ kd,         // [BH][T][D]
    unsigned short* __restrict__ vd)         // [BH][D][T]
{
  __shared__ unsigned short la[128 * 32];    // linear, 8 KB
  __shared__ unsigned short lb[128 * 32];
  const int tid = threadIdx.x;
  const int lane = tid & 63;
  const int wid = tid >> 6;
  const int l15 = lane & 15, lg = lane >> 4;
  const int wm = (wid & 1) * 64, wn = (wid >> 1) * 64;
  const int bm = blockIdx.x;
  const int wsel = blockIdx.y >> 3;          // 0=Q 1=K 2=V
  const int bnl = blockIdx.y & 7;

  const unsigned short* W = (wsel == 0) ? Wq : (wsel == 1) ? Wk : Wv;
  const float* bias = (wsel == 0) ? bq : (wsel == 1) ? bk : bv;

  const int srow = lane >> 2;                // 0..15 within segment
  const int sko  = (lane & 3) * 8;           // k-chunk 0/8/16/24

  f32x4 acc[4][4];
#pragma unroll
  for (int i = 0; i < 4; ++i)
#pragma unroll
    for (int j = 0; j < 4; ++j) acc[i][j] = f32x4{0.f, 0.f, 0.f, 0.f};

  for (int kt = 0; kt < CC / 32; ++kt) {
    __syncthreads();                         // prior frag reads done before overwrite
#pragma unroll
    for (int s = 0; s < 2; ++s) {
      const int seg = wid * 2 + s;           // 0..7 (16 rows each)
      const int row = seg * 16 + srow;
      gload16(&A[(bm * 128 + row) * CC + kt * 32 + sko], &la[seg * 512]);
      gload16(&W[(bnl * 128 + row) * CC + kt * 32 + sko], &lb[seg * 512]);
    }
    __syncthreads();                         // drains vmcnt(0): staged data visible
    bf16x8 af[4], bf[4];
#pragma unroll
    for (int mi = 0; mi < 4; ++mi)
      af[mi] = __builtin_bit_cast(bf16x8,
        *reinterpret_cast<const us8*>(&la[(wm + mi * 16 + l15) * 32 + lg * 8]));
#pragma unroll
    for (int ni = 0; ni < 4; ++ni)
      bf[ni] = __builtin_bit_cast(bf16x8,
        *reinterpret_cast<const us8*>(&lb[(wn + ni * 16 + l15) * 32 + lg * 8]));
#pragma unroll
    for (int mi = 0; mi < 4; ++mi)
#pragma unroll
      for (int ni = 0; ni < 4; ++ni)
        acc[mi][ni] = __builtin_amdgcn_mfma_f32_16x16x32_bf16(af[mi], bf[ni], acc[mi][ni], 0, 0, 0);
  }

  // epilogue: C/D col = lane&15, row = (lane>>4)*4 + r
#pragma unroll
  for (int ni = 0; ni < 4; ++ni) {
    const int nl = bnl * 128 + wn + ni * 16 + l15;   // 0..1023
    const float bvl = bias[nl];
    const int hh = nl >> 6, d = nl & (DD - 1);
#pragma unroll
    for (int mi = 0; mi < 4; ++mi) {
#pragma unroll
      for (int r = 0; r < 4; ++r) {
        const int m = bm * 128 + wm + mi * 16 + lg * 4 + r;
        const unsigned short bb = f2b(acc[mi][ni][r] + bvl);
        const int b = m >> 11, t = m & (TT - 1);
        if (wsel == 0)
          qd[((b * HH + hh) * TT + t) * DD + d] = bb;
        else if (wsel == 1)
          kd[((b * HH + hh) * TT + t) * DD + d] = bb;
        else
          vd[((b * HH + hh) * DD + d) * TT + t] = bb;
      }
    }
  }
}

// ---------------- output projection GEMM ----------------
// out[m,n] = sum_k y[m,k]*Wo[n,k] + bo[n], fp32 out. 128x64 tile, BK=32,
// grid (32,16) = 512 blocks -> 2 blocks/CU.
__global__ __launch_bounds__(256, 2) void k_gemm_o(
    const unsigned short* __restrict__ A,    // y bf16 [4096][1024]
    const unsigned short* __restrict__ W,    // Wo bf16 [1024][1024]
    const float* __restrict__ bias,
    float* __restrict__ out)
{
  __shared__ unsigned short la[128 * 32];
  __shared__ unsigned short lb[64 * 32];
  const int tid = threadIdx.x;
  const int lane = tid & 63;
  const int wid = tid >> 6;
  const int l15 = lane & 15, lg = lane >> 4;
  const int wm = (wid & 1) * 64, wn = (wid >> 1) * 32;
  const int bm = blockIdx.x, bn = blockIdx.y;

  const int srow = lane >> 2;
  const int sko  = (lane & 3) * 8;

  f32x4 acc[4][2];
#pragma unroll
  for (int i = 0; i < 4; ++i)
#pragma unroll
    for (int j = 0; j < 2; ++j) acc[i][j] = f32x4{0.f, 0.f, 0.f, 0.f};

  for (int kt = 0; kt < CC / 32; ++kt) {
    __syncthreads();
#pragma unroll
    for (int s = 0; s < 2; ++s) {
      const int seg = wid * 2 + s;
      gload16(&A[(bm * 128 + seg * 16 + srow) * CC + kt * 32 + sko], &la[seg * 512]);
    }
    gload16(&W[(bn * 64 + wid * 16 + srow) * CC + kt * 32 + sko], &lb[wid * 512]);
    __syncthreads();
    bf16x8 af[4], bf[2];
#pragma unroll
    for (int mi = 0; mi < 4; ++mi)
      af[mi] = __builtin_bit_cast(bf16x8,
        *reinterpret_cast<const us8*>(&la[(wm + mi * 16 + l15) * 32 + lg * 8]));
#pragma unroll
    for (int ni = 0; ni < 2; ++ni)
      bf[ni] = __builtin_bit_cast(bf16x8,
        *reinterpret_cast<const us8*>(&lb[(wn + ni * 16 + l15) * 32 + lg * 8]));
#pragma unroll
    for (int mi = 0; mi < 4; ++mi)
#pragma unroll
      for (int ni = 0; ni < 2; ++ni)
        acc[mi][ni] = __builtin_amdgcn_mfma_f32_16x16x32_bf16(af[mi], bf[ni], acc[mi][ni], 0, 0, 0);
  }

#pragma unroll
  for (int ni = 0; ni < 2; ++ni) {
    const int n = bn * 64 + wn + ni * 16 + l15;
    const float bvl = bias[n];
#pragma unroll
    for (int mi = 0; mi < 4; ++mi)
#pragma unroll
      for (int r = 0; r < 4; ++r) {
        const int m = bm * 128 + wm + mi * 16 + lg * 4 + r;
        out[m * CC + n] = acc[mi][ni][r] + bvl;
      }
  }
}

// ---------------- flash attention v2 (unchanged from round 6, verified) ----------------
__global__ __launch_bounds__(64) void k_attn(
    const unsigned short* __restrict__ Q,   // [BH][T][D] bf16
    const unsigned short* __restrict__ K,   // [BH][T][D] bf16
    const unsigned short* __restrict__ VT,  // [BH][D][T] bf16
    unsigned short* __restrict__ Y)         // [B][T][C] bf16
{
  __shared__ unsigned short pl[2][2][16][80];  // [set][qi][q-row][key], padded rows
  const int lane = threadIdx.x;
  const int l15 = lane & 15, lg = lane >> 4;
  const int bh = blockIdx.y;
  const int b = bh >> 4, h = bh & 15;
  const int p = blockIdx.x;                // 0..31
  const int qb0A = p * 32;                 // low q-block
  const int qb0B = (63 - p) * 32;          // high q-block
  const int nktA = (qb0A + 95) >> 6;
  const int nktB = (qb0B + 95) >> 6;       // nktA + nktB == 33 for all p

  const unsigned short* Qh = Q + bh * TT * DD;
  const unsigned short* Kh = K + bh * TT * DD;
  const unsigned short* Vh = VT + bh * DD * TT;

  auto ldq = [&](bf16x8 (&qf)[2][2], int qb0) {
#pragma unroll
    for (int qi = 0; qi < 2; ++qi)
#pragma unroll
      for (int kk = 0; kk < 2; ++kk)
        qf[qi][kk] = __builtin_bit_cast(bf16x8,
          *reinterpret_cast<const us8*>(&Qh[(qb0 + qi * 16 + l15) * DD + kk * 32 + lg * 8]));
  };
  auto ldk = [&](bf16x8 (&kf)[4][2], int kb) {
#pragma unroll
    for (int f = 0; f < 4; ++f)
#pragma unroll
      for (int kk = 0; kk < 2; ++kk)
        kf[f][kk] = __builtin_bit_cast(bf16x8,
          *reinterpret_cast<const us8*>(&Kh[(kb + f * 16 + l15) * DD + kk * 32 + lg * 8]));
  };
  auto ldv = [&](bf16x8 (&vf)[2][4], int kb) {
#pragma unroll
    for (int kk = 0; kk < 2; ++kk)
#pragma unroll
      for (int dc = 0; dc < 4; ++dc)
        vf[kk][dc] = __builtin_bit_cast(bf16x8,
          *reinterpret_cast<const us8*>(&Vh[(dc * 16 + l15) * TT + kb + kk * 32 + lg * 8]));
  };

  bf16x8 qfA[2][2], qfB[2][2];
  ldq(qfA, qb0A); ldq(qfB, qb0B);

  f32x4 oA[2][4], oB[2][4];
  float mrA[2], lrA[2], mrB[2], lrB[2];
#pragma unroll
  for (int qi = 0; qi < 2; ++qi) {
    mrA[qi] = -INFINITY; lrA[qi] = 0.f;
    mrB[qi] = -INFINITY; lrB[qi] = 0.f;
#pragma unroll
    for (int dc = 0; dc < 4; ++dc) {
      oA[qi][dc] = f32x4{0.f, 0.f, 0.f, 0.f};
      oB[qi][dc] = f32x4{0.f, 0.f, 0.f, 0.f};
    }
  }

  auto processSet = [&](const int qb0, const bf16x8 (&qf)[2][2], f32x4 (&o)[2][4],
                        float (&mr)[2], float (&lr)[2],
                        unsigned short (&plS)[2][16][80],
                        const bf16x8 (&kf)[4][2], const bf16x8 (&vf)[2][4],
                        const int kbase) {
    // S^T = K Q^T : C[row=key=lg*4+r][col=q=l15]
    f32x4 s[2][4];
#pragma unroll
    for (int qi = 0; qi < 2; ++qi)
#pragma unroll
      for (int f = 0; f < 4; ++f) {
        f32x4 t0 = __builtin_amdgcn_mfma_f32_16x16x32_bf16(kf[f][0], qf[qi][0],
                                                           f32x4{0.f,0.f,0.f,0.f}, 0, 0, 0);
        s[qi][f] = __builtin_amdgcn_mfma_f32_16x16x32_bf16(kf[f][1], qf[qi][1], t0, 0, 0, 0);
      }
    const bool needMask = (kbase + 63 > qb0);  // wave-uniform
#pragma unroll
    for (int qi = 0; qi < 2; ++qi) {
      const int qg = qb0 + qi * 16 + l15;
      float sv[4][4];
      float mt = -INFINITY;
#pragma unroll
      for (int f = 0; f < 4; ++f)
#pragma unroll
        for (int r = 0; r < 4; ++r) {
          float v = s[qi][f][r] * SCALE2;
          if (needMask) v = (kbase + f * 16 + lg * 4 + r <= qg) ? v : -INFINITY;
          sv[f][r] = v;
          mt = fmaxf(mt, v);
        }
      mt = fmaxf(mt, __shfl_xor(mt, 16));
      mt = fmaxf(mt, __shfl_xor(mt, 32));
      const float mn = fmaxf(mr[qi], mt);
      const float al = FEXP2(mr[qi] - mn);   // first tile: exp2(-inf)=0
      mr[qi] = mn;
      float rs = 0.f;
#pragma unroll
      for (int f = 0; f < 4; ++f) {
        const float p0 = FEXP2(sv[f][0] - mn), p1 = FEXP2(sv[f][1] - mn);
        const float p2 = FEXP2(sv[f][2] - mn), p3 = FEXP2(sv[f][3] - mn);
        rs += (p0 + p1) + (p2 + p3);
        bf16x4 pk;
        pk[0] = (__bf16)p0; pk[1] = (__bf16)p1; pk[2] = (__bf16)p2; pk[3] = (__bf16)p3;
        *reinterpret_cast<bf16x4*>(&plS[qi][l15][f * 16 + lg * 4]) = pk;  // keys contiguous
      }
      rs += __shfl_xor(rs, 16);
      rs += __shfl_xor(rs, 32);
      lr[qi] = lr[qi] * al + rs;
      float alr[4];
#pragma unroll
      for (int r = 0; r < 4; ++r) alr[r] = __shfl(al, lg * 4 + r);  // q remap for C-layout
#pragma unroll
      for (int dc = 0; dc < 4; ++dc)
#pragma unroll
        for (int r = 0; r < 4; ++r) o[qi][dc][r] *= alr[r];
    }
    asm volatile("s_waitcnt lgkmcnt(0)" ::: "memory");
    __builtin_amdgcn_sched_barrier(0);
    // PV: A = P[row=q][k=key] from LDS, B = V^T fragments
#pragma unroll
    for (int qi = 0; qi < 2; ++qi) {
      const bf16x8 pa0 = __builtin_bit_cast(bf16x8,
        *reinterpret_cast<const us8*>(&plS[qi][l15][lg * 8]));
      const bf16x8 pa1 = __builtin_bit_cast(bf16x8,
        *reinterpret_cast<const us8*>(&plS[qi][l15][32 + lg * 8]));
#pragma unroll
      for (int dc = 0; dc < 4; ++dc) {
        o[qi][dc] = __builtin_amdgcn_mfma_f32_16x16x32_bf16(pa0, vf[0][dc], o[qi][dc], 0, 0, 0);
        o[qi][dc] = __builtin_amdgcn_mfma_f32_16x16x32_bf16(pa1, vf[1][dc], o[qi][dc], 0, 0, 0);
      }
    }
  };

  // main loop, unrolled by 2 for register double-buffered K fragments
  bf16x8 kf0[4][2], kf1[4][2];
  ldk(kf0, 0);
  for (int kt = 0; kt < nktB; kt += 2) {
    bf16x8 vf0[2][4];
    ldv(vf0, kt * 64);
    const int nx1 = (kt + 1 < nktB) ? kt + 1 : nktB - 1;
    ldk(kf1, nx1 * 64);
    processSet(qb0B, qfB, oB, mrB, lrB, pl[0], kf0, vf0, kt * 64);
    if (kt < nktA)
      processSet(qb0A, qfA, oA, mrA, lrA, pl[1], kf0, vf0, kt * 64);
    if (kt + 1 < nktB) {
      bf16x8 vf1[2][4];
      ldv(vf1, (kt + 1) * 64);
      const int nx2 = (kt + 2 < nktB) ? kt + 2 : nktB - 1;
      ldk(kf0, nx2 * 64);
      processSet(qb0B, qfB, oB, mrB, lrB, pl[0], kf1, vf1, (kt + 1) * 64);
      if (kt + 1 < nktA)
        processSet(qb0A, qfA, oA, mrA, lrA, pl[1], kf1, vf1, (kt + 1) * 64);
    }
  }

  auto epi = [&](int qb0, f32x4 (&o)[2][4], float (&lr)[2]) {
#pragma unroll
    for (int qi = 0; qi < 2; ++qi) {
      float linv[4];
#pragma unroll
      for (int r = 0; r < 4; ++r) linv[r] = 1.f / __shfl(lr[qi], lg * 4 + r);
#pragma unroll
      for (int r = 0; r < 4; ++r) {
        const int t = qb0 + qi * 16 + lg * 4 + r;
#pragma unroll
        for (int dc = 0; dc < 4; ++dc)
          Y[(b * TT + t) * CC + h * DD + dc * 16 + l15] = f2b(o[qi][dc][r] * linv[r]);
      }
    }
  };
  epi(qb0B, oB, lrB);
  epi(qb0A, oA, lrA);
}

extern "C" void kernel_launch(void* const* d_in, const int* in_sizes, int n_in,
                              void* d_out, int out_size, void* d_ws, size_t ws_size,
                              hipStream_t stream) {
  const float* x  = (const float*)d_in[0];
  const float* Wq = (const float*)d_in[1];
  const float* bq = (const float*)d_in[2];
  const float* Wk = (const float*)d_in[3];
  const float* bk = (const float*)d_in[4];
  const float* Wv = (const float*)d_in[5];
  const float* bv = (const float*)d_in[6];
  const float* Wo = (const float*)d_in[7];
  const float* bo = (const float*)d_in[8];
  float* out = (float*)d_out;

  unsigned short* ws  = (unsigned short*)d_ws;
  unsigned short* xb  = ws;               // x bf16       [4096][1024]
  unsigned short* wqb = xb  + 4194304;    // Wq bf16
  unsigned short* wkb = wqb + 1048576;
  unsigned short* wvb = wkb + 1048576;
  unsigned short* wob = wvb + 1048576;
  unsigned short* qb  = wob + 1048576;    // Q  [BH][T][D]
  unsigned short* kb  = qb  + 4194304;    // K  [BH][T][D]
  unsigned short* vt  = kb  + 4194304;    // V^T [BH][D][T]
  unsigned short* yb  = xb;               // attn out [B][T][C] — aliases xb (dead after QKV GEMM)

  k_cvt<<<4096, 256, 0, stream>>>(x,  xb,  1048576);
  k_cvt<<<1024, 256, 0, stream>>>(Wq, wqb, 262144);
  k_cvt<<<1024, 256, 0, stream>>>(Wk, wkb, 262144);
  k_cvt<<<1024, 256, 0, stream>>>(Wv, wvb, 262144);
  k_cvt<<<1024, 256, 0, stream>>>(Wo, wob, 262144);

  k_gemm_qkv<<<dim3(32, 24), 256, 0, stream>>>(xb, wqb, wkb, wvb, bq, bk, bv, qb, kb, vt);

  k_attn<<<dim3(32, 32), 64, 0, stream>>>(qb, kb, vt, yb);

  k_gemm_o<<<dim3(32, 16), 256, 0, stream>>>(yb, wob, bo, out);
}